// Round 2
// baseline (243.726 us; speedup 1.0000x reference)
//
#include <hip/hip_runtime.h>
#include <cstdint>

typedef _Float16 half8 __attribute__((ext_vector_type(8)));
typedef float f32x4 __attribute__((ext_vector_type(4)));

#define LN_EPS 1e-5f

__device__ __forceinline__ void gl2lds16(const void* g, void* l) {
  __builtin_amdgcn_global_load_lds((const __attribute__((address_space(1))) uint32_t*)g,
                                   (__attribute__((address_space(3))) uint32_t*)l, 16, 0, 0);
}

__device__ __forceinline__ float dot4(float4 a, float4 b) {
  return a.x*b.x + a.y*b.y + a.z*b.z + a.w*b.w;
}

// ---------------- K1 (fused): blocks 0..63 compute mask; blocks 64.. compute x_emb.
// mask role: per block 4 p-rows: LN(emb_prompt) -> x_prompt -> scores vs LN(emb_column) -> softmax.
// All global row reads are wave-cooperative (64 lanes x float4 across a 256-float row = coalesced),
// reductions via butterfly shuffles. Avoids the round-1 per-thread strided row reads
// (64 cache-line requests per load instr) that made the 3 small kernels latency-bound.
// xemb role: 4 b's per block (4x fewer feb/few L2 re-reads), blocked fp16 output [c/8][b*256+d][c%8].
__global__ __launch_bounds__(256) void k_fused(
    const float* __restrict__ x, const float* __restrict__ few, const float* __restrict__ feb,
    const float* __restrict__ ln_emb_w, const float* __restrict__ ln_emb_b,
    const float* __restrict__ emb_pr, const float* __restrict__ lnp_w, const float* __restrict__ lnp_b,
    const float* __restrict__ prev, const float* __restrict__ W, const float* __restrict__ Wb,
    const float* __restrict__ emb_col, const float* __restrict__ lnc_w, const float* __restrict__ lnc_b,
    float* __restrict__ mask_f32, _Float16* __restrict__ mask_f16, _Float16* __restrict__ emb)
{
  __shared__ __align__(16) union SMem {
    struct {                 // mask role (~18.3 KB)
      float xin[4][512];     // [r][0..255]=LN(emb_prompt), [256..511]=prev
      float xq[4][256];      // x_prompt rows
      float cmu[256], crs[256];
      float sc[4][256];      // scores
      float4 wr1[4], wr2[4];
    } m;
    struct {                 // xemb role (32.25 KB)
      float v[32][256];
      float mu[32], rs[32];
    } e;
  } sm;

  int t = threadIdx.x, w = t >> 6, lane = t & 63;

  if (blockIdx.x < 64) {
    // ================= mask role =================
    int pb = blockIdx.x * 4;
    // --- step 1: wave w does LN of emb_prompt row pb+w; stash [ln | prev] in LDS
    {
      int p = pb + w;
      float4 v = ((const float4*)emb_pr)[p * 64 + lane];
      float s1 = v.x + v.y + v.z + v.w;
      float s2 = v.x*v.x + v.y*v.y + v.z*v.z + v.w*v.w;
      #pragma unroll
      for (int o = 32; o > 0; o >>= 1) { s1 += __shfl_xor(s1, o); s2 += __shfl_xor(s2, o); }
      float mu = s1 * (1.0f/256.0f);
      float var = s2 * (1.0f/256.0f) - mu*mu;
      float rs = rsqrtf(var + LN_EPS);
      float4 w4 = ((const float4*)lnp_w)[lane];
      float4 b4 = ((const float4*)lnp_b)[lane];
      float4 y;
      y.x = (v.x-mu)*rs*w4.x + b4.x;  y.y = (v.y-mu)*rs*w4.y + b4.y;
      y.z = (v.z-mu)*rs*w4.z + b4.z;  y.w = (v.w-mu)*rs*w4.w + b4.w;
      ((float4*)sm.m.xin[w])[lane] = y;
      ((float4*)sm.m.xin[w])[64 + lane] = ((const float4*)prev)[p * 64 + lane];
    }
    // --- step 1b: LN stats of emb_column rows, wave-cooperative (64 rows/wave)
    for (int i = 0; i < 64; ++i) {
      int c = w * 64 + i;
      float4 v = ((const float4*)emb_col)[c * 64 + lane];
      float s1 = v.x + v.y + v.z + v.w;
      float s2 = v.x*v.x + v.y*v.y + v.z*v.z + v.w*v.w;
      #pragma unroll
      for (int o = 32; o > 0; o >>= 1) { s1 += __shfl_xor(s1, o); s2 += __shfl_xor(s2, o); }
      if (lane == 0) {
        float mu = s1 * (1.0f/256.0f);
        float var = s2 * (1.0f/256.0f) - mu*mu;
        sm.m.cmu[c] = mu;
        sm.m.crs[c] = rsqrtf(var + LN_EPS);
      }
    }
    __syncthreads();
    // --- step 2: x_prompt, wave-cooperative over output d (coalesced W row reads)
    {
      float4 xa[4], xb[4];
      #pragma unroll
      for (int r = 0; r < 4; ++r) {
        xa[r] = ((const float4*)sm.m.xin[r])[lane];
        xb[r] = ((const float4*)sm.m.xin[r])[64 + lane];
      }
      for (int i = 0; i < 64; ++i) {
        int d = w * 64 + i;
        float4 wa = ((const float4*)W)[d * 128 + lane];
        float4 wc = ((const float4*)W)[d * 128 + 64 + lane];
        float a0 = dot4(wa, xa[0]) + dot4(wc, xb[0]);
        float a1 = dot4(wa, xa[1]) + dot4(wc, xb[1]);
        float a2 = dot4(wa, xa[2]) + dot4(wc, xb[2]);
        float a3 = dot4(wa, xa[3]) + dot4(wc, xb[3]);
        #pragma unroll
        for (int o = 32; o > 0; o >>= 1) {
          a0 += __shfl_xor(a0, o); a1 += __shfl_xor(a1, o);
          a2 += __shfl_xor(a2, o); a3 += __shfl_xor(a3, o);
        }
        if (lane == 0) {
          float bb = Wb[d];
          sm.m.xq[0][d] = a0 + bb + emb_pr[(pb+0)*256 + d];
          sm.m.xq[1][d] = a1 + bb + emb_pr[(pb+1)*256 + d];
          sm.m.xq[2][d] = a2 + bb + emb_pr[(pb+2)*256 + d];
          sm.m.xq[3][d] = a3 + bb + emb_pr[(pb+3)*256 + d];
        }
      }
    }
    __syncthreads();
    // --- step 3: scores sc[r][c] = x_prompt[r] . LN(emb_col[c]), wave-cooperative
    {
      float4 lw4 = ((const float4*)lnc_w)[lane];
      float4 lb4 = ((const float4*)lnc_b)[lane];
      float4 xr[4];
      #pragma unroll
      for (int r = 0; r < 4; ++r) xr[r] = ((const float4*)sm.m.xq[r])[lane];
      for (int i = 0; i < 64; ++i) {
        int c = w * 64 + i;
        float4 v = ((const float4*)emb_col)[c * 64 + lane];
        float mu = sm.m.cmu[c], rs = sm.m.crs[c];
        float4 nc;
        nc.x = (v.x-mu)*rs*lw4.x + lb4.x;  nc.y = (v.y-mu)*rs*lw4.y + lb4.y;
        nc.z = (v.z-mu)*rs*lw4.z + lb4.z;  nc.w = (v.w-mu)*rs*lw4.w + lb4.w;
        float a0 = dot4(nc, xr[0]), a1 = dot4(nc, xr[1]);
        float a2 = dot4(nc, xr[2]), a3 = dot4(nc, xr[3]);
        #pragma unroll
        for (int o = 32; o > 0; o >>= 1) {
          a0 += __shfl_xor(a0, o); a1 += __shfl_xor(a1, o);
          a2 += __shfl_xor(a2, o); a3 += __shfl_xor(a3, o);
        }
        if (lane == 0) {
          sm.m.sc[0][c] = a0; sm.m.sc[1][c] = a1;
          sm.m.sc[2][c] = a2; sm.m.sc[3][c] = a3;
        }
      }
    }
    __syncthreads();
    // --- step 4: softmax over c (threads-as-c)
    {
      float val[4];
      #pragma unroll
      for (int r = 0; r < 4; ++r) val[r] = sm.m.sc[r][t];
      float m0[4] = {val[0], val[1], val[2], val[3]};
      #pragma unroll
      for (int o = 32; o > 0; o >>= 1)
        #pragma unroll
        for (int r = 0; r < 4; ++r) m0[r] = fmaxf(m0[r], __shfl_xor(m0[r], o));
      if (lane == 0) sm.m.wr1[w] = make_float4(m0[0], m0[1], m0[2], m0[3]);
      __syncthreads();
      float4 a0 = sm.m.wr1[0], a1 = sm.m.wr1[1], a2 = sm.m.wr1[2], a3 = sm.m.wr1[3];
      float M[4] = { fmaxf(fmaxf(a0.x,a1.x), fmaxf(a2.x,a3.x)),
                     fmaxf(fmaxf(a0.y,a1.y), fmaxf(a2.y,a3.y)),
                     fmaxf(fmaxf(a0.z,a1.z), fmaxf(a2.z,a3.z)),
                     fmaxf(fmaxf(a0.w,a1.w), fmaxf(a2.w,a3.w)) };
      float e[4], s[4];
      #pragma unroll
      for (int r = 0; r < 4; ++r) { e[r] = expf(val[r] - M[r]); s[r] = e[r]; }
      #pragma unroll
      for (int o = 32; o > 0; o >>= 1)
        #pragma unroll
        for (int r = 0; r < 4; ++r) s[r] += __shfl_xor(s[r], o);
      if (lane == 0) sm.m.wr2[w] = make_float4(s[0], s[1], s[2], s[3]);
      __syncthreads();
      float4 b0 = sm.m.wr2[0], b1 = sm.m.wr2[1], b2 = sm.m.wr2[2], b3 = sm.m.wr2[3];
      float S[4] = { b0.x+b1.x+b2.x+b3.x, b0.y+b1.y+b2.y+b3.y,
                     b0.z+b1.z+b2.z+b3.z, b0.w+b1.w+b2.w+b3.w };
      #pragma unroll
      for (int r = 0; r < 4; ++r) {
        float mv = e[r] / S[r];
        mask_f32[(pb+r)*256 + t] = mv;
        mask_f16[(pb+r)*256 + t] = (_Float16)mv;
      }
    }
  } else {
    // ================= xemb role =================
    int bid = blockIdx.x - 64;
    int cg = bid & 31, bg = bid >> 5;
    float fw[8], fb[8];
    #pragma unroll
    for (int cl = 0; cl < 8; ++cl) {
      int c = cg*8 + cl;
      fw[cl] = few[c*256 + t];
      fb[cl] = feb[c*256 + t];
    }
    float v[4][8];
    #pragma unroll
    for (int j = 0; j < 4; ++j) {
      int b = bg*4 + j;
      #pragma unroll
      for (int cl = 0; cl < 8; ++cl) {
        float xv = x[b*256 + cg*8 + cl];
        v[j][cl] = fmaxf(fb[cl] + xv*fw[cl], 0.f);
        sm.e.v[j*8 + cl][t] = v[j][cl];
      }
    }
    __syncthreads();
    #pragma unroll
    for (int jj = 0; jj < 8; ++jj) {
      int row = w*8 + jj;
      float4 a = ((const float4*)sm.e.v[row])[lane];
      float s1 = a.x + a.y + a.z + a.w;
      float s2 = a.x*a.x + a.y*a.y + a.z*a.z + a.w*a.w;
      #pragma unroll
      for (int o = 32; o > 0; o >>= 1) { s1 += __shfl_xor(s1, o); s2 += __shfl_xor(s2, o); }
      if (lane == 0) {
        float mu = s1 * (1.0f/256.0f);
        float var = s2 * (1.0f/256.0f) - mu*mu;
        sm.e.mu[row] = mu;
        sm.e.rs[row] = rsqrtf(var + LN_EPS);
      }
    }
    __syncthreads();
    float lw = ln_emb_w[t], lb = ln_emb_b[t];
    #pragma unroll
    for (int j = 0; j < 4; ++j) {
      half8 h;
      #pragma unroll
      for (int cl = 0; cl < 8; ++cl) {
        int row = j*8 + cl;
        h[cl] = (_Float16)((v[j][cl] - sm.e.mu[row]) * sm.e.rs[row] * lw + lb);
      }
      ((uint4*)emb)[(size_t)cg*65536 + (size_t)(bg*4 + j)*256 + t] = *(const uint4*)&h;
    }
  }
}

// ---------------- K2: out[b,p,d] = (1+ew[p]) * sum_c mask[p,c]*emb[c,(b,d)] + mask[b,p]*eb[b]
// GEMM M=256(p) N=65536(b*256+d) K=256(c). 128x128 tile, BK=128 (2 K-iters), fp16 MFMA.
// A fragments loaded straight from L2 (16B-contiguous rows of the fp16 mask); B staged
// via global_load_lds width=16 into [k8][n][8] blocked LDS.
__global__ __launch_bounds__(256) void k_gemm(
    const _Float16* __restrict__ Bmat, const _Float16* __restrict__ Amask,
    const float* __restrict__ mask_f32,
    const float* __restrict__ ew, const float* __restrict__ eb,
    float* __restrict__ out)
{
  __shared__ __align__(16) _Float16 Bs[16 * 128 * 8];   // 32 KB
  int t = threadIdx.x, w = t >> 6, lane = t & 63;
  int lm = lane & 15, quad = lane >> 4;
  int wm = (w & 1) * 64, wn = (w >> 1) * 64;
  int p0 = blockIdx.x * 128;
  int n0 = blockIdx.y * 128;

  f32x4 acc[4][4];
  #pragma unroll
  for (int i = 0; i < 4; ++i)
    #pragma unroll
    for (int j = 0; j < 4; ++j)
      acc[i][j] = (f32x4){0.f, 0.f, 0.f, 0.f};

  #pragma unroll
  for (int kb = 0; kb < 2; ++kb) {
    if (kb) __syncthreads();
    #pragma unroll
    for (int i = 0; i < 8; ++i) {
      int u = i*256 + t;
      int chi = u >> 7, np = u & 127;
      gl2lds16(Bmat + (size_t)(kb*16 + chi)*524288 + (size_t)(n0 + np)*8, Bs + (size_t)u*8);
    }
    __syncthreads();
    #pragma unroll
    for (int ks = 0; ks < 4; ++ks) {
      int k0 = kb*128 + ks*32 + quad*8;
      half8 af[4], bf[4];
      #pragma unroll
      for (int mt = 0; mt < 4; ++mt)
        af[mt] = *(const half8*)(Amask + (size_t)(p0 + wm + mt*16 + lm)*256 + k0);
      #pragma unroll
      for (int nt = 0; nt < 4; ++nt)
        bf[nt] = *(const half8*)(Bs + ((ks*4 + quad)*128 + wn + nt*16 + lm)*8);
      #pragma unroll
      for (int mt = 0; mt < 4; ++mt)
        #pragma unroll
        for (int nt = 0; nt < 4; ++nt)
          acc[mt][nt] = __builtin_amdgcn_mfma_f32_16x16x32_f16(af[mt], bf[nt], acc[mt][nt], 0, 0, 0);
    }
  }

  // epilogue: C/D layout col=lane&15, row=quad*4+reg
  int b = n0 >> 8;
  float ebv = eb[b];
  #pragma unroll
  for (int mt = 0; mt < 4; ++mt) {
    float sp[4], tb[4];
    #pragma unroll
    for (int r = 0; r < 4; ++r) {
      int p = p0 + wm + mt*16 + quad*4 + r;
      sp[r] = 1.0f + ew[p];
      tb[r] = mask_f32[b*256 + p] * ebv;
    }
    #pragma unroll
    for (int nt = 0; nt < 4; ++nt) {
      int d = (n0 & 255) + wn + nt*16 + lm;
      #pragma unroll
      for (int r = 0; r < 4; ++r) {
        int p = p0 + wm + mt*16 + quad*4 + r;
        out[((size_t)b << 16) + ((size_t)p << 8) + d] = acc[mt][nt][r] * sp[r] + tb[r];
      }
    }
  }
}

extern "C" void kernel_launch(void* const* d_in, const int* in_sizes, int n_in,
                              void* d_out, int out_size, void* d_ws, size_t ws_size,
                              hipStream_t stream) {
  const float* x        = (const float*)d_in[0];
  const float* prev     = (const float*)d_in[1];
  const float* few      = (const float*)d_in[2];
  const float* feb      = (const float*)d_in[3];
  const float* ln_emb_w = (const float*)d_in[4];
  const float* ln_emb_b = (const float*)d_in[5];
  const float* ln_col_w = (const float*)d_in[6];
  const float* ln_col_b = (const float*)d_in[7];
  const float* ln_pr_w  = (const float*)d_in[8];
  const float* ln_pr_b  = (const float*)d_in[9];
  const float* dimp_w   = (const float*)d_in[10];
  const float* dimp_b   = (const float*)d_in[11];
  const float* emb_col  = (const float*)d_in[12];
  const float* emb_pr   = (const float*)d_in[13];
  const float* ew       = (const float*)d_in[14];
  const float* eb       = (const float*)d_in[15];
  float* out = (float*)d_out;

  char* wsb = (char*)d_ws;
  _Float16* ws_emb    = (_Float16*)(wsb);                // 33,554,432 B
  float*    ws_mask   = (float*)(wsb + 33554432);        //    262,144 B
  _Float16* ws_mask_h = (_Float16*)(wsb + 33816576);     //    131,072 B

  k_fused<<<dim3(64 + 2048), dim3(256), 0, stream>>>(
      x, few, feb, ln_emb_w, ln_emb_b,
      emb_pr, ln_pr_w, ln_pr_b, prev, dimp_w, dimp_b,
      emb_col, ln_col_w, ln_col_b,
      ws_mask, ws_mask_h, ws_emb);
  k_gemm<<<dim3(2, 512), dim3(256), 0, stream>>>(ws_emb, ws_mask_h, ws_mask, ew, eb, out);
}

// Round 3
// 195.544 us; speedup vs baseline: 1.2464x; 1.2464x over previous
//
#include <hip/hip_runtime.h>
#include <cstdint>

typedef _Float16 half8 __attribute__((ext_vector_type(8)));
typedef float f32x4 __attribute__((ext_vector_type(4)));

#define LN_EPS 1e-5f

__device__ __forceinline__ void gl2lds16(const void* g, void* l) {
  __builtin_amdgcn_global_load_lds((const __attribute__((address_space(1))) uint32_t*)g,
                                   (__attribute__((address_space(3))) uint32_t*)l, 16, 0, 0);
}

__device__ __forceinline__ float dot4(float4 a, float4 b) {
  return a.x*b.x + a.y*b.y + a.z*b.z + a.w*b.w;
}

// K1 (fused): blocks 0..63 = mask role (4 p-rows each); blocks 64.. = xemb role.
// Mask role design rule (round-2 post-mortem): NO shuffle butterflies inside loops —
// each ds_bpermute is ~40-120cyc of dependent latency. Threads own outputs; the only
// cross-lane ops are one 2-level quad reduce per k-loop and one butterfly in softmax.
// W / emb_col reads use quad-strip mapping (thread t -> row t>>2, k-strip t&3) so each
// quad consumes whole 64B lines (16 full lines per instr).
__global__ __launch_bounds__(256) void k_fused(
    const float* __restrict__ x, const float* __restrict__ few, const float* __restrict__ feb,
    const float* __restrict__ ln_emb_w, const float* __restrict__ ln_emb_b,
    const float* __restrict__ emb_pr, const float* __restrict__ lnp_w, const float* __restrict__ lnp_b,
    const float* __restrict__ prev, const float* __restrict__ W, const float* __restrict__ Wb,
    const float* __restrict__ emb_col, const float* __restrict__ lnc_w, const float* __restrict__ lnc_b,
    float* __restrict__ mask_f32, _Float16* __restrict__ mask_f16, _Float16* __restrict__ emb)
{
  __shared__ __align__(16) union SMem {
    struct {                 // mask role (~16.1 KB)
      float xin[4][512];     // [r][0..255]=LN(emb_prompt), [256..511]=prev
      float xq[4][256];      // x_prompt rows
      float sc[4][256];      // scores
      float4 wr1[4], wr2[4];
    } m;
    struct {                 // xemb role (32.25 KB)
      float v[32][256];
      float mu[32], rs[32];
    } e;
  } sm;

  int t = threadIdx.x, w = t >> 6, lane = t & 63;

  if (blockIdx.x < 64) {
    // ================= mask role =================
    int pb = blockIdx.x * 4;
    int q = t & 3;        // k/d strip within quad
    int g = t >> 2;       // 0..63 across block

    // --- P1: wave w does LN of emb_prompt row pb+w; stash [ln | prev] in LDS
    {
      int p = pb + w;
      float4 v = ((const float4*)emb_pr)[p * 64 + lane];
      float s1 = v.x + v.y + v.z + v.w;
      float s2 = v.x*v.x + v.y*v.y + v.z*v.z + v.w*v.w;
      #pragma unroll
      for (int o = 32; o > 0; o >>= 1) { s1 += __shfl_xor(s1, o); s2 += __shfl_xor(s2, o); }
      float mu = s1 * (1.0f/256.0f);
      float var = s2 * (1.0f/256.0f) - mu*mu;
      float rs = rsqrtf(var + LN_EPS);
      float4 w4 = ((const float4*)lnp_w)[lane];
      float4 b4 = ((const float4*)lnp_b)[lane];
      float4 y;
      y.x = (v.x-mu)*rs*w4.x + b4.x;  y.y = (v.y-mu)*rs*w4.y + b4.y;
      y.z = (v.z-mu)*rs*w4.z + b4.z;  y.w = (v.w-mu)*rs*w4.w + b4.w;
      ((float4*)sm.m.xin[w])[lane] = y;
      ((float4*)sm.m.xin[w])[64 + lane] = ((const float4*)prev)[p * 64 + lane];
    }
    __syncthreads();

    // --- P2: x_prompt[r][d] = sum_k xin[r][k]*W[d][k]; thread covers 4 d's (one per pass),
    //         k-strip q. No in-loop reductions; xin LDS reads are quad-multicast.
    {
      float acc[4][4];   // [pass][r]
      #pragma unroll
      for (int pp = 0; pp < 4; ++pp)
        #pragma unroll
        for (int r = 0; r < 4; ++r) acc[pp][r] = 0.f;
      #pragma unroll 4
      for (int j = 0; j < 32; ++j) {
        int k4 = j*4 + q;
        float4 xv[4];
        #pragma unroll
        for (int r = 0; r < 4; ++r) xv[r] = ((const float4*)sm.m.xin[r])[k4];
        #pragma unroll
        for (int pp = 0; pp < 4; ++pp) {
          int d = pp*64 + g;
          float4 wv = ((const float4*)(W + (size_t)d*512))[k4];
          #pragma unroll
          for (int r = 0; r < 4; ++r) acc[pp][r] += dot4(wv, xv[r]);
        }
      }
      #pragma unroll
      for (int pp = 0; pp < 4; ++pp)
        #pragma unroll
        for (int r = 0; r < 4; ++r) {
          acc[pp][r] += __shfl_xor(acc[pp][r], 1);
          acc[pp][r] += __shfl_xor(acc[pp][r], 2);
        }
      if (q == 0) {
        #pragma unroll
        for (int pp = 0; pp < 4; ++pp) {
          int d = pp*64 + g;
          float bb = Wb[d];
          #pragma unroll
          for (int r = 0; r < 4; ++r)
            sm.m.xq[r][d] = acc[pp][r] + bb + emb_pr[(pb+r)*256 + d];
        }
      }
    }
    __syncthreads();

    // --- P3: S[r][c] = x_prompt[r] . LN(emb_col[c]); thread covers 4 c's, d-strip q.
    //         Column stats computed in-thread (two sweeps, 2nd L1-hot).
    {
      float s1[4] = {0,0,0,0}, s2[4] = {0,0,0,0};
      #pragma unroll 4
      for (int j = 0; j < 16; ++j) {
        int k4 = j*4 + q;
        #pragma unroll
        for (int pp = 0; pp < 4; ++pp) {
          int c = pp*64 + g;
          float4 v = ((const float4*)(emb_col + (size_t)c*256))[k4];
          s1[pp] += v.x + v.y + v.z + v.w;
          s2[pp] += v.x*v.x + v.y*v.y + v.z*v.z + v.w*v.w;
        }
      }
      float mu[4], rs[4];
      #pragma unroll
      for (int pp = 0; pp < 4; ++pp) {
        s1[pp] += __shfl_xor(s1[pp], 1);  s1[pp] += __shfl_xor(s1[pp], 2);
        s2[pp] += __shfl_xor(s2[pp], 1);  s2[pp] += __shfl_xor(s2[pp], 2);
        mu[pp] = s1[pp] * (1.0f/256.0f);
        float var = s2[pp] * (1.0f/256.0f) - mu[pp]*mu[pp];
        rs[pp] = rsqrtf(var + LN_EPS);
      }
      float acc[4][4];   // [pass(c)][r]
      #pragma unroll
      for (int pp = 0; pp < 4; ++pp)
        #pragma unroll
        for (int r = 0; r < 4; ++r) acc[pp][r] = 0.f;
      #pragma unroll 4
      for (int j = 0; j < 16; ++j) {
        int k4 = j*4 + q;
        float4 lw4 = ((const float4*)lnc_w)[k4];
        float4 lb4 = ((const float4*)lnc_b)[k4];
        float4 xv[4];
        #pragma unroll
        for (int r = 0; r < 4; ++r) xv[r] = ((const float4*)sm.m.xq[r])[k4];
        #pragma unroll
        for (int pp = 0; pp < 4; ++pp) {
          int c = pp*64 + g;
          float4 v = ((const float4*)(emb_col + (size_t)c*256))[k4];
          float4 nc;
          nc.x = (v.x-mu[pp])*rs[pp]*lw4.x + lb4.x;
          nc.y = (v.y-mu[pp])*rs[pp]*lw4.y + lb4.y;
          nc.z = (v.z-mu[pp])*rs[pp]*lw4.z + lb4.z;
          nc.w = (v.w-mu[pp])*rs[pp]*lw4.w + lb4.w;
          #pragma unroll
          for (int r = 0; r < 4; ++r) acc[pp][r] += dot4(nc, xv[r]);
        }
      }
      #pragma unroll
      for (int pp = 0; pp < 4; ++pp)
        #pragma unroll
        for (int r = 0; r < 4; ++r) {
          acc[pp][r] += __shfl_xor(acc[pp][r], 1);
          acc[pp][r] += __shfl_xor(acc[pp][r], 2);
        }
      if (q == 0) {
        #pragma unroll
        for (int pp = 0; pp < 4; ++pp)
          #pragma unroll
          for (int r = 0; r < 4; ++r)
            sm.m.sc[r][pp*64 + g] = acc[pp][r];
      }
    }
    __syncthreads();

    // --- P4: softmax over c (threads-as-c); single butterfly, not in a loop.
    {
      float val[4];
      #pragma unroll
      for (int r = 0; r < 4; ++r) val[r] = sm.m.sc[r][t];
      float m0[4] = {val[0], val[1], val[2], val[3]};
      #pragma unroll
      for (int o = 32; o > 0; o >>= 1)
        #pragma unroll
        for (int r = 0; r < 4; ++r) m0[r] = fmaxf(m0[r], __shfl_xor(m0[r], o));
      if (lane == 0) sm.m.wr1[w] = make_float4(m0[0], m0[1], m0[2], m0[3]);
      __syncthreads();
      float4 a0 = sm.m.wr1[0], a1 = sm.m.wr1[1], a2 = sm.m.wr1[2], a3 = sm.m.wr1[3];
      float M[4] = { fmaxf(fmaxf(a0.x,a1.x), fmaxf(a2.x,a3.x)),
                     fmaxf(fmaxf(a0.y,a1.y), fmaxf(a2.y,a3.y)),
                     fmaxf(fmaxf(a0.z,a1.z), fmaxf(a2.z,a3.z)),
                     fmaxf(fmaxf(a0.w,a1.w), fmaxf(a2.w,a3.w)) };
      float e[4], s[4];
      #pragma unroll
      for (int r = 0; r < 4; ++r) { e[r] = expf(val[r] - M[r]); s[r] = e[r]; }
      #pragma unroll
      for (int o = 32; o > 0; o >>= 1)
        #pragma unroll
        for (int r = 0; r < 4; ++r) s[r] += __shfl_xor(s[r], o);
      if (lane == 0) sm.m.wr2[w] = make_float4(s[0], s[1], s[2], s[3]);
      __syncthreads();
      float4 b0 = sm.m.wr2[0], b1 = sm.m.wr2[1], b2 = sm.m.wr2[2], b3 = sm.m.wr2[3];
      float S[4] = { b0.x+b1.x+b2.x+b3.x, b0.y+b1.y+b2.y+b3.y,
                     b0.z+b1.z+b2.z+b3.z, b0.w+b1.w+b2.w+b3.w };
      #pragma unroll
      for (int r = 0; r < 4; ++r) {
        float mv = e[r] / S[r];
        mask_f32[(pb+r)*256 + t] = mv;
        mask_f16[(pb+r)*256 + t] = (_Float16)mv;
      }
    }
  } else {
    // ================= xemb role =================
    int bid = blockIdx.x - 64;
    int cg = bid & 31, bg = bid >> 5;
    float fw[8], fb[8];
    #pragma unroll
    for (int cl = 0; cl < 8; ++cl) {
      int c = cg*8 + cl;
      fw[cl] = few[c*256 + t];
      fb[cl] = feb[c*256 + t];
    }
    float v[4][8];
    #pragma unroll
    for (int j = 0; j < 4; ++j) {
      int b = bg*4 + j;
      #pragma unroll
      for (int cl = 0; cl < 8; ++cl) {
        float xv = x[b*256 + cg*8 + cl];
        v[j][cl] = fmaxf(fb[cl] + xv*fw[cl], 0.f);
        sm.e.v[j*8 + cl][t] = v[j][cl];
      }
    }
    __syncthreads();
    #pragma unroll
    for (int jj = 0; jj < 8; ++jj) {
      int row = w*8 + jj;
      float4 a = ((const float4*)sm.e.v[row])[lane];
      float s1 = a.x + a.y + a.z + a.w;
      float s2 = a.x*a.x + a.y*a.y + a.z*a.z + a.w*a.w;
      #pragma unroll
      for (int o = 32; o > 0; o >>= 1) { s1 += __shfl_xor(s1, o); s2 += __shfl_xor(s2, o); }
      if (lane == 0) {
        float mu = s1 * (1.0f/256.0f);
        float var = s2 * (1.0f/256.0f) - mu*mu;
        sm.e.mu[row] = mu;
        sm.e.rs[row] = rsqrtf(var + LN_EPS);
      }
    }
    __syncthreads();
    float lw = ln_emb_w[t], lb = ln_emb_b[t];
    #pragma unroll
    for (int j = 0; j < 4; ++j) {
      half8 h;
      #pragma unroll
      for (int cl = 0; cl < 8; ++cl) {
        int row = j*8 + cl;
        h[cl] = (_Float16)((v[j][cl] - sm.e.mu[row]) * sm.e.rs[row] * lw + lb);
      }
      ((uint4*)emb)[(size_t)cg*65536 + (size_t)(bg*4 + j)*256 + t] = *(const uint4*)&h;
    }
  }
}

// K2: GEMM (round-1 version, measured <49us): M=256(p) N=65536(b*256+d) K=256(c).
// 128x128 tile, BK=64, fp16 MFMA; B via global_load_lds w=16; A via VGPR->padded LDS.
__global__ __launch_bounds__(256) void k_gemm(
    const _Float16* __restrict__ Bmat, const _Float16* __restrict__ Amask,
    const float* __restrict__ mask_f32,
    const float* __restrict__ ew, const float* __restrict__ eb,
    float* __restrict__ out)
{
  __shared__ __align__(16) _Float16 As[128 * 72];      // padded [m][72]
  __shared__ __align__(16) _Float16 Bs[8 * 128 * 8];   // [k8][n][8]
  int t = threadIdx.x, w = t >> 6, lane = t & 63;
  int lm = lane & 15, quad = lane >> 4;
  int wm = (w & 1) * 64, wn = (w >> 1) * 64;
  int p0 = blockIdx.x * 128;
  int n0 = blockIdx.y * 128;

  f32x4 acc[4][4];
  #pragma unroll
  for (int i = 0; i < 4; ++i)
    #pragma unroll
    for (int j = 0; j < 4; ++j)
      acc[i][j] = (f32x4){0.f, 0.f, 0.f, 0.f};

  for (int kb = 0; kb < 4; ++kb) {
    int k0 = kb * 64;
    if (kb) __syncthreads();
    #pragma unroll
    for (int i = 0; i < 4; ++i) {
      int u = i*256 + t;
      int chi = u >> 7, np = u & 127;
      gl2lds16(Bmat + (size_t)(kb*8 + chi)*524288 + (size_t)(n0 + np)*8, Bs + (size_t)u*8);
    }
    uint4 av[4];
    #pragma unroll
    for (int i = 0; i < 4; ++i) {
      int u = i*256 + t;
      int m = u >> 3, k8 = u & 7;
      av[i] = *(const uint4*)(Amask + (size_t)(p0 + m)*256 + k0 + k8*8);
    }
    #pragma unroll
    for (int i = 0; i < 4; ++i) {
      int u = i*256 + t;
      int m = u >> 3, k8 = u & 7;
      *(uint4*)(As + m*72 + k8*8) = av[i];
    }
    __syncthreads();
    #pragma unroll
    for (int ks = 0; ks < 2; ++ks) {
      half8 af[4], bf[4];
      #pragma unroll
      for (int mt = 0; mt < 4; ++mt)
        af[mt] = *(const half8*)(As + (wm + mt*16 + lm)*72 + ks*32 + quad*8);
      #pragma unroll
      for (int nt = 0; nt < 4; ++nt)
        bf[nt] = *(const half8*)(Bs + ((ks*4 + quad)*128 + wn + nt*16 + lm)*8);
      #pragma unroll
      for (int mt = 0; mt < 4; ++mt)
        #pragma unroll
        for (int nt = 0; nt < 4; ++nt)
          acc[mt][nt] = __builtin_amdgcn_mfma_f32_16x16x32_f16(af[mt], bf[nt], acc[mt][nt], 0, 0, 0);
    }
  }

  int b = n0 >> 8;
  float ebv = eb[b];
  #pragma unroll
  for (int mt = 0; mt < 4; ++mt) {
    float sp[4], tb[4];
    #pragma unroll
    for (int r = 0; r < 4; ++r) {
      int p = p0 + wm + mt*16 + quad*4 + r;
      sp[r] = 1.0f + ew[p];
      tb[r] = mask_f32[b*256 + p] * ebv;
    }
    #pragma unroll
    for (int nt = 0; nt < 4; ++nt) {
      int d = (n0 & 255) + wn + nt*16 + lm;
      #pragma unroll
      for (int r = 0; r < 4; ++r) {
        int p = p0 + wm + mt*16 + quad*4 + r;
        out[((size_t)b << 16) + ((size_t)p << 8) + d] = acc[mt][nt][r] * sp[r] + tb[r];
      }
    }
  }
}

extern "C" void kernel_launch(void* const* d_in, const int* in_sizes, int n_in,
                              void* d_out, int out_size, void* d_ws, size_t ws_size,
                              hipStream_t stream) {
  const float* x        = (const float*)d_in[0];
  const float* prev     = (const float*)d_in[1];
  const float* few      = (const float*)d_in[2];
  const float* feb      = (const float*)d_in[3];
  const float* ln_emb_w = (const float*)d_in[4];
  const float* ln_emb_b = (const float*)d_in[5];
  const float* ln_col_w = (const float*)d_in[6];
  const float* ln_col_b = (const float*)d_in[7];
  const float* ln_pr_w  = (const float*)d_in[8];
  const float* ln_pr_b  = (const float*)d_in[9];
  const float* dimp_w   = (const float*)d_in[10];
  const float* dimp_b   = (const float*)d_in[11];
  const float* emb_col  = (const float*)d_in[12];
  const float* emb_pr   = (const float*)d_in[13];
  const float* ew       = (const float*)d_in[14];
  const float* eb       = (const float*)d_in[15];
  float* out = (float*)d_out;

  char* wsb = (char*)d_ws;
  _Float16* ws_emb    = (_Float16*)(wsb);                // 33,554,432 B
  float*    ws_mask   = (float*)(wsb + 33554432);        //    262,144 B
  _Float16* ws_mask_h = (_Float16*)(wsb + 33816576);     //    131,072 B

  k_fused<<<dim3(64 + 2048), dim3(256), 0, stream>>>(
      x, few, feb, ln_emb_w, ln_emb_b,
      emb_pr, ln_pr_w, ln_pr_b, prev, dimp_w, dimp_b,
      emb_col, ln_col_w, ln_col_b,
      ws_mask, ws_mask_h, ws_emb);
  k_gemm<<<dim3(2, 512), dim3(256), 0, stream>>>(ws_emb, ws_mask_h, ws_mask, ew, eb, out);
}

// Round 4
// 159.000 us; speedup vs baseline: 1.5329x; 1.2298x over previous
//
#include <hip/hip_runtime.h>
#include <cstdint>

typedef _Float16 half8 __attribute__((ext_vector_type(8)));
typedef float f32x4 __attribute__((ext_vector_type(4)));

#define LN_EPS 1e-5f

__device__ __forceinline__ float dot4(float4 a, float4 b) {
  return a.x*b.x + a.y*b.y + a.z*b.z + a.w*b.w;
}

// ============ K1 (k_pre): blocks 0..255 = mask (1 p-row each); 256..2303 = LN stats.
// stats role: wave-autonomous (no LDS, no barriers): wave = (b, 8 c-rows), lane = d/4.
// 16 independent butterfly streams pipeline; stats2[b][c] = {mu, rs}.
// mask role: 1 p per block; P1 in registers per-wave (redundant, no sync); P2/P3 use
// quad-strip mapping (thread -> (row g=t>>2, k-strip q=t&3)) so quads consume whole
// 64B lines; only 2-level quad reduces inside loops (round-2 lesson: no in-loop butterflies).
__global__ __launch_bounds__(256) void k_pre(
    const float* __restrict__ x, const float* __restrict__ few, const float* __restrict__ feb,
    const float* __restrict__ emb_pr, const float* __restrict__ lnp_w, const float* __restrict__ lnp_b,
    const float* __restrict__ prev, const float* __restrict__ W, const float* __restrict__ Wb,
    const float* __restrict__ emb_col, const float* __restrict__ lnc_w, const float* __restrict__ lnc_b,
    float2* __restrict__ stats2, float* __restrict__ mask_f32, _Float16* __restrict__ mask_f16)
{
  __shared__ __align__(16) struct {
    float xin[512];          // [LN(emb_pr[p]) | prev[p]]
    float xq[256];           // x_prompt row
    float sc[256];           // scores
    float wr1[4], wr2[4];
  } sm;

  int t = threadIdx.x, w = t >> 6, lane = t & 63;

  if (blockIdx.x >= 256) {
    // ================= stats role =================
    int bid = blockIdx.x - 256;
    int b = bid >> 3;
    int cg = (bid & 7) * 4 + w;
    int c0 = cg * 8;
    float xv[8];
    #pragma unroll
    for (int j = 0; j < 8; ++j) xv[j] = x[b*256 + c0 + j];
    float s1[8], s2[8];
    #pragma unroll
    for (int j = 0; j < 8; ++j) { s1[j] = 0.f; s2[j] = 0.f; }
    #pragma unroll
    for (int j = 0; j < 8; ++j) {
      float4 fw = ((const float4*)few)[(c0+j)*64 + lane];
      float4 fb = ((const float4*)feb)[(c0+j)*64 + lane];
      float4 v;
      v.x = fmaxf(fb.x + xv[j]*fw.x, 0.f);
      v.y = fmaxf(fb.y + xv[j]*fw.y, 0.f);
      v.z = fmaxf(fb.z + xv[j]*fw.z, 0.f);
      v.w = fmaxf(fb.w + xv[j]*fw.w, 0.f);
      s1[j] += v.x + v.y + v.z + v.w;
      s2[j] += v.x*v.x + v.y*v.y + v.z*v.z + v.w*v.w;
    }
    #pragma unroll
    for (int o = 32; o > 0; o >>= 1) {
      #pragma unroll
      for (int j = 0; j < 8; ++j) { s1[j] += __shfl_xor(s1[j], o); s2[j] += __shfl_xor(s2[j], o); }
    }
    float mu[8], rs[8];
    #pragma unroll
    for (int j = 0; j < 8; ++j) {
      mu[j] = s1[j] * (1.0f/256.0f);
      float var = s2[j] * (1.0f/256.0f) - mu[j]*mu[j];
      rs[j] = rsqrtf(var + LN_EPS);
    }
    float muv = mu[0], rsv = rs[0];
    #pragma unroll
    for (int j = 1; j < 8; ++j) {
      muv = (lane == j) ? mu[j] : muv;
      rsv = (lane == j) ? rs[j] : rsv;
    }
    if (lane < 8) stats2[b*256 + c0 + lane] = make_float2(muv, rsv);
    return;
  }

  // ================= mask role (p = blockIdx.x) =================
  int p = blockIdx.x;
  int q = t & 3, g = t >> 2;

  // P1: each wave redundantly LNs emb_pr[p]; wave 0 stores [ln|prev] to LDS.
  {
    float4 v = ((const float4*)emb_pr)[p*64 + lane];
    float s1 = v.x + v.y + v.z + v.w;
    float s2 = v.x*v.x + v.y*v.y + v.z*v.z + v.w*v.w;
    #pragma unroll
    for (int o = 32; o > 0; o >>= 1) { s1 += __shfl_xor(s1, o); s2 += __shfl_xor(s2, o); }
    float mu = s1 * (1.0f/256.0f);
    float var = s2 * (1.0f/256.0f) - mu*mu;
    float rsv = rsqrtf(var + LN_EPS);
    float4 w4 = ((const float4*)lnp_w)[lane];
    float4 b4 = ((const float4*)lnp_b)[lane];
    float4 y;
    y.x = (v.x-mu)*rsv*w4.x + b4.x;  y.y = (v.y-mu)*rsv*w4.y + b4.y;
    y.z = (v.z-mu)*rsv*w4.z + b4.z;  y.w = (v.w-mu)*rsv*w4.w + b4.w;
    if (w == 0) {
      ((float4*)sm.xin)[lane] = y;
      ((float4*)sm.xin)[64 + lane] = ((const float4*)prev)[p*64 + lane];
    }
  }
  __syncthreads();

  // P2: x_prompt[d] = sum_k xin[k]*W[d][k] + Wb[d] + emb_pr[p][d]
  {
    float acc[4] = {0.f, 0.f, 0.f, 0.f};
    #pragma unroll 4
    for (int j = 0; j < 32; ++j) {
      int k4 = j*4 + q;
      float4 xv = ((const float4*)sm.xin)[k4];
      #pragma unroll
      for (int pp = 0; pp < 4; ++pp) {
        int d = pp*64 + g;
        float4 wv = ((const float4*)W)[d*128 + k4];
        acc[pp] += dot4(wv, xv);
      }
    }
    #pragma unroll
    for (int pp = 0; pp < 4; ++pp) {
      acc[pp] += __shfl_xor(acc[pp], 1);
      acc[pp] += __shfl_xor(acc[pp], 2);
    }
    if (q == 0) {
      #pragma unroll
      for (int pp = 0; pp < 4; ++pp) {
        int d = pp*64 + g;
        sm.xq[d] = acc[pp] + Wb[d] + emb_pr[p*256 + d];
      }
    }
  }
  __syncthreads();

  // P3: sc[c] = x_prompt . LN(emb_col[c]); in-thread col stats (2 sweeps, 2nd L1-hot).
  {
    float s1[4] = {0,0,0,0}, s2[4] = {0,0,0,0};
    #pragma unroll 4
    for (int j = 0; j < 16; ++j) {
      int k4 = j*4 + q;
      #pragma unroll
      for (int pp = 0; pp < 4; ++pp) {
        float4 v = ((const float4*)emb_col)[(pp*64+g)*64 + k4];
        s1[pp] += v.x + v.y + v.z + v.w;
        s2[pp] += v.x*v.x + v.y*v.y + v.z*v.z + v.w*v.w;
      }
    }
    float mu[4], rs[4];
    #pragma unroll
    for (int pp = 0; pp < 4; ++pp) {
      s1[pp] += __shfl_xor(s1[pp], 1);  s1[pp] += __shfl_xor(s1[pp], 2);
      s2[pp] += __shfl_xor(s2[pp], 1);  s2[pp] += __shfl_xor(s2[pp], 2);
      mu[pp] = s1[pp] * (1.0f/256.0f);
      float var = s2[pp] * (1.0f/256.0f) - mu[pp]*mu[pp];
      rs[pp] = rsqrtf(var + LN_EPS);
    }
    float acc[4] = {0.f, 0.f, 0.f, 0.f};
    #pragma unroll 4
    for (int j = 0; j < 16; ++j) {
      int k4 = j*4 + q;
      float4 lw4 = ((const float4*)lnc_w)[k4];
      float4 lb4 = ((const float4*)lnc_b)[k4];
      float4 xv = ((const float4*)sm.xq)[k4];
      #pragma unroll
      for (int pp = 0; pp < 4; ++pp) {
        float4 v = ((const float4*)emb_col)[(pp*64+g)*64 + k4];
        float4 nc;
        nc.x = (v.x-mu[pp])*rs[pp]*lw4.x + lb4.x;
        nc.y = (v.y-mu[pp])*rs[pp]*lw4.y + lb4.y;
        nc.z = (v.z-mu[pp])*rs[pp]*lw4.z + lb4.z;
        nc.w = (v.w-mu[pp])*rs[pp]*lw4.w + lb4.w;
        acc[pp] += dot4(nc, xv);
      }
    }
    #pragma unroll
    for (int pp = 0; pp < 4; ++pp) {
      acc[pp] += __shfl_xor(acc[pp], 1);
      acc[pp] += __shfl_xor(acc[pp], 2);
    }
    if (q == 0) {
      #pragma unroll
      for (int pp = 0; pp < 4; ++pp) sm.sc[pp*64 + g] = acc[pp];
    }
  }
  __syncthreads();

  // P4: softmax over 256 c
  {
    float val = sm.sc[t];
    float m0 = val;
    #pragma unroll
    for (int o = 32; o > 0; o >>= 1) m0 = fmaxf(m0, __shfl_xor(m0, o));
    if (lane == 0) sm.wr1[w] = m0;
    __syncthreads();
    float M = fmaxf(fmaxf(sm.wr1[0], sm.wr1[1]), fmaxf(sm.wr1[2], sm.wr1[3]));
    float e = expf(val - M);
    float s = e;
    #pragma unroll
    for (int o = 32; o > 0; o >>= 1) s += __shfl_xor(s, o);
    if (lane == 0) sm.wr2[w] = s;
    __syncthreads();
    float S = sm.wr2[0] + sm.wr2[1] + sm.wr2[2] + sm.wr2[3];
    float mv = e / S;
    mask_f32[p*256 + t] = mv;
    mask_f16[p*256 + t] = (_Float16)mv;
  }
}

// ============ K2 (k_main): fused x_emb + GEMM + epilogue.
// Tile M=256 (all p) x N=64 (one b, one 64-d slab), K=256 (c). 1024 blocks.
// Producer phase per 64-c chunk: thread (dl=t&63, wave grp) computes 16 c's of
// v=relu(feb+x*few), normalizes with stats2[b][c], packs fp16 into the proven
// conflict-free [k8][n][8] LDS layout via two ds_write_b128. x_emb never touches HBM.
// A (mask fp16) fragments read straight from L2 (16B contiguous per lane).
__global__ __launch_bounds__(256) void k_main(
    const float* __restrict__ x, const float* __restrict__ few, const float* __restrict__ feb,
    const float* __restrict__ ln_emb_w, const float* __restrict__ ln_emb_b,
    const float2* __restrict__ stats2,
    const _Float16* __restrict__ mask_f16, const float* __restrict__ mask_f32,
    const float* __restrict__ ew, const float* __restrict__ eb,
    float* __restrict__ out)
{
  __shared__ __align__(16) _Float16 Bs[8 * 64 * 8];   // 8 KB, [k8][n][8]
  __shared__ float xrow[256];
  __shared__ float2 srow[256];

  int t = threadIdx.x, w = t >> 6, lane = t & 63;
  int lm = lane & 15, quad = lane >> 4;
  int b = blockIdx.x >> 2;
  int ds = (blockIdx.x & 3) * 64;
  int dl = t & 63;

  xrow[t] = x[b*256 + t];
  srow[t] = stats2[b*256 + t];
  float lwv = ln_emb_w[ds + dl];
  float lbv = ln_emb_b[ds + dl];

  f32x4 acc[4][4];
  #pragma unroll
  for (int i = 0; i < 4; ++i)
    #pragma unroll
    for (int j = 0; j < 4; ++j)
      acc[i][j] = (f32x4){0.f, 0.f, 0.f, 0.f};

  __syncthreads();

  for (int kb = 0; kb < 4; ++kb) {
    // producer: 16 c's (c_local = w*16 + j) at fixed d = ds + dl
    half8 h0, h1;
    #pragma unroll
    for (int j = 0; j < 16; ++j) {
      int cl = kb*64 + w*16 + j;
      float fw = few[cl*256 + ds + dl];
      float fb = feb[cl*256 + ds + dl];
      float xc = xrow[cl];
      float2 st = srow[cl];
      float v = fmaxf(fb + xc*fw, 0.f);
      _Float16 hh = (_Float16)((v - st.x) * st.y * lwv + lbv);
      if (j < 8) h0[j] = hh; else h1[j-8] = hh;
    }
    *(half8*)(Bs + ((w*2 + 0)*64 + dl)*8) = h0;
    *(half8*)(Bs + ((w*2 + 1)*64 + dl)*8) = h1;
    __syncthreads();

    #pragma unroll
    for (int ks = 0; ks < 2; ++ks) {
      half8 af[4], bf[4];
      #pragma unroll
      for (int mt = 0; mt < 4; ++mt)
        af[mt] = *(const half8*)(mask_f16 + (size_t)(w*64 + mt*16 + lm)*256 + kb*64 + ks*32 + quad*8);
      #pragma unroll
      for (int nt = 0; nt < 4; ++nt)
        bf[nt] = *(const half8*)(Bs + ((ks*4 + quad)*64 + nt*16 + lm)*8);
      #pragma unroll
      for (int mt = 0; mt < 4; ++mt)
        #pragma unroll
        for (int nt = 0; nt < 4; ++nt)
          acc[mt][nt] = __builtin_amdgcn_mfma_f32_16x16x32_f16(af[mt], bf[nt], acc[mt][nt], 0, 0, 0);
    }
    __syncthreads();
  }

  // epilogue: C/D layout col=lane&15 (d), row=quad*4+r (p)
  float ebv = eb[b];
  #pragma unroll
  for (int mt = 0; mt < 4; ++mt) {
    float sp[4], tb[4];
    #pragma unroll
    for (int r = 0; r < 4; ++r) {
      int p = w*64 + mt*16 + quad*4 + r;
      sp[r] = 1.0f + ew[p];
      tb[r] = mask_f32[b*256 + p] * ebv;
    }
    #pragma unroll
    for (int nt = 0; nt < 4; ++nt) {
      int d = ds + nt*16 + lm;
      #pragma unroll
      for (int r = 0; r < 4; ++r) {
        int p = w*64 + mt*16 + quad*4 + r;
        out[((size_t)b << 16) + ((size_t)p << 8) + d] = acc[mt][nt][r] * sp[r] + tb[r];
      }
    }
  }
}

extern "C" void kernel_launch(void* const* d_in, const int* in_sizes, int n_in,
                              void* d_out, int out_size, void* d_ws, size_t ws_size,
                              hipStream_t stream) {
  const float* x        = (const float*)d_in[0];
  const float* prev     = (const float*)d_in[1];
  const float* few      = (const float*)d_in[2];
  const float* feb      = (const float*)d_in[3];
  const float* ln_emb_w = (const float*)d_in[4];
  const float* ln_emb_b = (const float*)d_in[5];
  const float* ln_col_w = (const float*)d_in[6];
  const float* ln_col_b = (const float*)d_in[7];
  const float* ln_pr_w  = (const float*)d_in[8];
  const float* ln_pr_b  = (const float*)d_in[9];
  const float* dimp_w   = (const float*)d_in[10];
  const float* dimp_b   = (const float*)d_in[11];
  const float* emb_col  = (const float*)d_in[12];
  const float* emb_pr   = (const float*)d_in[13];
  const float* ew       = (const float*)d_in[14];
  const float* eb       = (const float*)d_in[15];
  float* out = (float*)d_out;

  char* wsb = (char*)d_ws;
  float2*   ws_stats  = (float2*)(wsb);                  // 524,288 B
  float*    ws_mask   = (float*)(wsb + 524288);          // 262,144 B
  _Float16* ws_mask_h = (_Float16*)(wsb + 786432);       // 131,072 B

  k_pre<<<dim3(256 + 2048), dim3(256), 0, stream>>>(
      x, few, feb,
      emb_pr, ln_pr_w, ln_pr_b, prev, dimp_w, dimp_b,
      emb_col, ln_col_w, ln_col_b,
      ws_stats, ws_mask, ws_mask_h);
  k_main<<<dim3(1024), dim3(256), 0, stream>>>(
      x, few, feb, ln_emb_w, ln_emb_b,
      ws_stats, ws_mask_h, ws_mask, ew, eb, out);
}